// Round 2
// baseline (1286.770 us; speedup 1.0000x reference)
//
#include <hip/hip_runtime.h>
#include <stdint.h>

#define CB 32
#define CT 512
#define CK 256

// One workgroup (256 threads, 4 waves) per batch chain.
// Thread j owns column j. E[:,j] = exp(trans[:,j]) resides in VGPRs (256 f32).
// Per step: publish reference m = alpha[0], share p = exp(alpha - m) via LDS,
// dot with E column, alpha_new = m + log(s) + emit.
__global__ __launch_bounds__(256, 1) void crf_chain_kernel(
    const float* __restrict__ emissions,    // [B,T,K]
    const int* __restrict__ tags,           // [B,T]
    const int* __restrict__ mask,           // [B,T] (bool -> int32 in harness)
    const float* __restrict__ trans,        // [K,K]
    float* __restrict__ ws)                 // ws[0..31]=log_den, ws[32..63]=log_num
{
    const int b = blockIdx.x;
    const int j = threadIdx.x;
    const int wid = j >> 6;
    const int lane = j & 63;

    __shared__ float pbuf[CK];
    __shared__ float mslot;
    __shared__ float red[8];

    const float* emB = emissions + (size_t)b * CT * CK;
    const int* tagB = tags + b * CT;
    const int* maskB = mask + b * CT;

    // ---------------- numerator (joint log-likelihood) ----------------
    float num = 0.f;
    for (int t = j; t < CT; t += 256) {
        float mf = maskB[t] ? 1.f : 0.f;
        num += emB[(size_t)t * CK + tagB[t]] * mf;
        if (t >= 1) {
            num += trans[tagB[t - 1] * CK + tagB[t]] * mf;
        }
    }
    #pragma unroll
    for (int off = 32; off > 0; off >>= 1) num += __shfl_down(num, off, 64);
    if (lane == 0) red[wid] = num;
    __syncthreads();
    if (j == 0) ws[CB + b] = red[0] + red[1] + red[2] + red[3];
    __syncthreads();

    // ---------------- load exp(trans) column j into registers ----------------
    float e[CK];
    #pragma unroll
    for (int i = 0; i < CK; ++i) {
        e[i] = __expf(trans[i * CK + j]);
    }

    // ---------------- forward recursion ----------------
    float aj = emB[j];                    // alpha at t=0
    float emit_next = emB[CK + j];        // prefetch t=1

    for (int t = 1; t < CT; ++t) {
        float emit_t = emit_next;
        if (t + 1 < CT) emit_next = emB[(size_t)(t + 1) * CK + j];
        const int mk = maskB[t];

        if (j == 0) mslot = aj;
        __syncthreads();
        const float m = mslot;
        pbuf[j] = __expf(aj - m);
        __syncthreads();

        float s0 = 0.f, s1 = 0.f, s2 = 0.f, s3 = 0.f;
        #pragma unroll
        for (int i = 0; i < CK; i += 4) {
            const float4 p4 = *reinterpret_cast<const float4*>(&pbuf[i]); // broadcast
            s0 = fmaf(p4.x, e[i + 0], s0);
            s1 = fmaf(p4.y, e[i + 1], s1);
            s2 = fmaf(p4.z, e[i + 2], s2);
            s3 = fmaf(p4.w, e[i + 3], s3);
        }
        const float s = (s0 + s1) + (s2 + s3);
        const float anew = m + __logf(s) + emit_t;
        aj = mk ? anew : aj;
        // no extra barrier needed: next iteration's phase-1 barrier orders
        // this iteration's pbuf reads against the next pbuf/mslot writes.
    }

    // ---------------- final logsumexp over j ----------------
    float mx = aj;
    #pragma unroll
    for (int off = 32; off > 0; off >>= 1) mx = fmaxf(mx, __shfl_down(mx, off, 64));
    mx = __shfl(mx, 0, 64);
    if (lane == 0) red[wid] = mx;
    __syncthreads();
    const float gmx = fmaxf(fmaxf(red[0], red[1]), fmaxf(red[2], red[3]));
    float ex = __expf(aj - gmx);
    #pragma unroll
    for (int off = 32; off > 0; off >>= 1) ex += __shfl_down(ex, off, 64);
    if (lane == 0) red[4 + wid] = ex;
    __syncthreads();
    if (j == 0) ws[b] = gmx + __logf(red[4] + red[5] + red[6] + red[7]);
}

__global__ void crf_finalize_kernel(const float* __restrict__ ws,
                                    float* __restrict__ out) {
    float v = 0.f;
    if ((int)threadIdx.x < CB) v = ws[threadIdx.x] - ws[CB + threadIdx.x];
    #pragma unroll
    for (int off = 32; off > 0; off >>= 1) v += __shfl_down(v, off, 64);
    if (threadIdx.x == 0) out[0] = v * (1.f / CB);
}

extern "C" void kernel_launch(void* const* d_in, const int* in_sizes, int n_in,
                              void* d_out, int out_size, void* d_ws, size_t ws_size,
                              hipStream_t stream) {
    const float* emissions = (const float*)d_in[0];
    const int* tags = (const int*)d_in[1];
    const int* mask = (const int*)d_in[2];
    const float* trans = (const float*)d_in[3];
    float* out = (float*)d_out;
    float* ws = (float*)d_ws;

    crf_chain_kernel<<<CB, 256, 0, stream>>>(emissions, tags, mask, trans, ws);
    crf_finalize_kernel<<<1, 64, 0, stream>>>(ws, out);
}

// Round 3
// 545.466 us; speedup vs baseline: 2.3590x; 2.3590x over previous
//
#include <hip/hip_runtime.h>
#include <stdint.h>

#define CB 32
#define CT 512
#define CK 256

typedef _Float16 half2_t __attribute__((ext_vector_type(2)));

#if __has_builtin(__builtin_amdgcn_fdot2)
__device__ inline float dot2f(half2_t a, half2_t b, float c) {
    return __builtin_amdgcn_fdot2(a, b, c, false);
}
#else
__device__ inline float dot2f(half2_t a, half2_t b, float c) {
    asm("v_dot2_f32_f16 %0, %1, %2, %0" : "+v"(c) : "v"(a), "v"(b));
    return c;
}
#endif

// Barrier that drains LDS ops but leaves global-load (vmcnt) prefetches in
// flight across the barrier (plain __syncthreads would drain vmcnt and
// serialize the emissions prefetch every step).
__device__ inline void lds_barrier() {
    asm volatile("s_waitcnt lgkmcnt(0)\n\ts_barrier" ::: "memory");
}

// One workgroup (256 threads, 4 waves) per batch chain; thread j owns state j.
// E[:,j] = exp(trans[:,j]) lives in VGPRs as 128 packed f16 pairs.
// Per step: per-wave max m_w (shuffle), publish p = exp(a - m_w) <= 1 as f16,
// 4 wave-block partial dots via v_dot2_f32_f16, combine with exp(m_w - M).
__global__ __launch_bounds__(256, 1) void crf_chain_kernel(
    const float* __restrict__ emissions,    // [B,T,K]
    const int* __restrict__ tags,           // [B,T]
    const int* __restrict__ mask,           // [B,T] (bool -> int32)
    const float* __restrict__ trans,        // [K,K]
    float* __restrict__ ws)                 // ws[0..31]=log_den, ws[32..63]=log_num
{
    const int b = blockIdx.x;
    const int j = threadIdx.x;
    const int wid = j >> 6;
    const int lane = j & 63;

    __shared__ __align__(16) _Float16 pbuf[CK];
    __shared__ __align__(16) float wmax[4];
    __shared__ float mask_lds[CT];
    __shared__ float red[8];

    const float* emB = emissions + (size_t)b * CT * CK;
    const int* tagB = tags + b * CT;
    const int* maskB = mask + b * CT;

    // ---------------- numerator (joint log-likelihood) ----------------
    float num = 0.f;
    for (int t = j; t < CT; t += 256) {
        float mf = maskB[t] ? 1.f : 0.f;
        num += emB[(size_t)t * CK + tagB[t]] * mf;
        if (t >= 1) num += trans[tagB[t - 1] * CK + tagB[t]] * mf;
    }
    #pragma unroll
    for (int off = 32; off > 0; off >>= 1) num += __shfl_down(num, off, 64);
    if (lane == 0) red[wid] = num;
    __syncthreads();
    if (j == 0) ws[CB + b] = red[0] + red[1] + red[2] + red[3];

    // mask as float in LDS (avoids per-step SMEM load that lgkmcnt would drain)
    for (int t = j; t < CT; t += 256) mask_lds[t] = maskB[t] ? 1.f : 0.f;

    // ---------------- E column j as 128 packed f16 pairs in VGPRs ----------------
    half2_t e2[CK / 2];
    #pragma unroll
    for (int i = 0; i < CK / 2; ++i) {
        float e0 = __expf(trans[(2 * i) * CK + j]);
        float e1 = __expf(trans[(2 * i + 1) * CK + j]);
        e2[i] = __builtin_bit_cast(half2_t, __builtin_amdgcn_cvt_pkrtz(e0, e1));
    }
    __syncthreads();

    // ---------------- forward recursion ----------------
    float aj = emB[j];                    // alpha at t=0
    float emit_next = emB[CK + j];        // prefetch t=1

    for (int t = 1; t < CT; ++t) {
        const float emit_t = emit_next;
        const int nxt = (t + 1 < CT) ? (t + 1) : (CT - 1);
        emit_next = emB[(size_t)nxt * CK + j];   // stays in flight across barriers

        // phase A: per-wave max, publish p
        float m = aj;
        #pragma unroll
        for (int off = 1; off < 64; off <<= 1) m = fmaxf(m, __shfl_xor(m, off, 64));
        if (lane == 0) wmax[wid] = m;
        pbuf[j] = (_Float16)__expf(aj - m);
        lds_barrier();

        // phase B: 4 wave-block partial dots + scaled combine
        const float mkf = mask_lds[t];
        float sw[4];
        #pragma unroll
        for (int w = 0; w < 4; ++w) {
            float acc = 0.f;
            #pragma unroll
            for (int c = 0; c < 8; ++c) {
                const float4 q = *reinterpret_cast<const float4*>(&pbuf[w * 64 + c * 8]);
                acc = dot2f(__builtin_bit_cast(half2_t, q.x), e2[w * 32 + c * 4 + 0], acc);
                acc = dot2f(__builtin_bit_cast(half2_t, q.y), e2[w * 32 + c * 4 + 1], acc);
                acc = dot2f(__builtin_bit_cast(half2_t, q.z), e2[w * 32 + c * 4 + 2], acc);
                acc = dot2f(__builtin_bit_cast(half2_t, q.w), e2[w * 32 + c * 4 + 3], acc);
            }
            sw[w] = acc;
        }
        const float4 wm = *reinterpret_cast<const float4*>(wmax);
        const float M = fmaxf(fmaxf(wm.x, wm.y), fmaxf(wm.z, wm.w));
        float s = __expf(wm.x - M) * sw[0];
        s = fmaf(__expf(wm.y - M), sw[1], s);
        s = fmaf(__expf(wm.z - M), sw[2], s);
        s = fmaf(__expf(wm.w - M), sw[3], s);
        const float anew = M + __logf(s) + emit_t;
        aj = (mkf != 0.f) ? anew : aj;
        lds_barrier();   // protect pbuf/wmax reads from next step's writes
    }

    // ---------------- final logsumexp over j ----------------
    float mx = aj;
    #pragma unroll
    for (int off = 32; off > 0; off >>= 1) mx = fmaxf(mx, __shfl_down(mx, off, 64));
    mx = __shfl(mx, 0, 64);
    if (lane == 0) red[wid] = mx;
    __syncthreads();
    const float gmx = fmaxf(fmaxf(red[0], red[1]), fmaxf(red[2], red[3]));
    float ex = __expf(aj - gmx);
    #pragma unroll
    for (int off = 32; off > 0; off >>= 1) ex += __shfl_down(ex, off, 64);
    if (lane == 0) red[4 + wid] = ex;
    __syncthreads();
    if (j == 0) ws[b] = gmx + __logf(red[4] + red[5] + red[6] + red[7]);
}

__global__ void crf_finalize_kernel(const float* __restrict__ ws,
                                    float* __restrict__ out) {
    float v = 0.f;
    if ((int)threadIdx.x < CB) v = ws[threadIdx.x] - ws[CB + threadIdx.x];
    #pragma unroll
    for (int off = 32; off > 0; off >>= 1) v += __shfl_down(v, off, 64);
    if (threadIdx.x == 0) out[0] = v * (1.f / CB);
}

extern "C" void kernel_launch(void* const* d_in, const int* in_sizes, int n_in,
                              void* d_out, int out_size, void* d_ws, size_t ws_size,
                              hipStream_t stream) {
    const float* emissions = (const float*)d_in[0];
    const int* tags = (const int*)d_in[1];
    const int* mask = (const int*)d_in[2];
    const float* trans = (const float*)d_in[3];
    float* out = (float*)d_out;
    float* ws = (float*)d_ws;

    crf_chain_kernel<<<CB, 256, 0, stream>>>(emissions, tags, mask, trans, ws);
    crf_finalize_kernel<<<1, 64, 0, stream>>>(ws, out);
}

// Round 4
// 538.771 us; speedup vs baseline: 2.3883x; 1.0124x over previous
//
#include <hip/hip_runtime.h>
#include <stdint.h>

#define CB 32
#define CT 512
#define CK 256

typedef _Float16 half2_t __attribute__((ext_vector_type(2)));

__device__ inline float dot2f(half2_t a, half2_t b, float c) {
#if __has_builtin(__builtin_amdgcn_fdot2)
    return __builtin_amdgcn_fdot2(a, b, c, false);
#else
    asm("v_dot2_f32_f16 %0, %1, %2, %0" : "+v"(c) : "v"(a), "v"(b));
    return c;
#endif
}

__device__ inline half2_t bch2(float f) { return __builtin_bit_cast(half2_t, f); }
__device__ inline half2_t bch2u(uint32_t u) { return __builtin_bit_cast(half2_t, u); }

__device__ inline uint32_t pk2(float a, float b) {
    return __builtin_bit_cast(uint32_t,
        __builtin_amdgcn_cvt_pkrtz(__expf(a), __expf(b)));
}

// Barrier that drains LDS ops but leaves global-load (vmcnt) prefetches in
// flight across the barrier.
__device__ inline void lds_barrier() {
    asm volatile("s_waitcnt lgkmcnt(0)\n\ts_barrier" ::: "memory");
}

// E var n covers transition rows 8n..8n+7 for this thread's column j:
// .x = rows(8n,8n+1), .y = (+2,+3), .z = (+4,+5), .w = (+6,+7), each a half2.
#define MKE(n) uint4 E##n; { const float* tp = trans + (n) * 8 * CK + j;   \
    E##n.x = pk2(tp[0], tp[CK]);                                           \
    E##n.y = pk2(tp[2 * CK], tp[3 * CK]);                                  \
    E##n.z = pk2(tp[4 * CK], tp[5 * CK]);                                  \
    E##n.w = pk2(tp[6 * CK], tp[7 * CK]); }

// 8 p-values (broadcast float4 = 4 half2) dotted against E var EV.
#define DOTC(EV, base, accA, accB) {                                        \
    const float4 q = *reinterpret_cast<const float4*>(&pbuf[(base)]);       \
    accA = dot2f(bch2(q.x), bch2u(EV.x), accA);                             \
    accB = dot2f(bch2(q.y), bch2u(EV.y), accB);                             \
    accA = dot2f(bch2(q.z), bch2u(EV.z), accA);                             \
    accB = dot2f(bch2(q.w), bch2u(EV.w), accB); }

// One workgroup (256 threads, 4 waves) per batch chain; thread j owns state j.
// E[:,j]=exp(trans[:,j]) lives in 32 named uint4 SSA values (128 VGPRs) so it
// CANNOT be demoted to scratch (the R2/R3 failure: array -> alloca -> scratch).
__global__ __launch_bounds__(256, 1) void crf_chain_kernel(
    const float* __restrict__ emissions,    // [B,T,K]
    const int* __restrict__ tags,           // [B,T]
    const int* __restrict__ mask,           // [B,T] (bool -> int32)
    const float* __restrict__ trans,        // [K,K]
    float* __restrict__ ws)                 // ws[0..31]=log_den, ws[32..63]=log_num
{
    const int b = blockIdx.x;
    const int j = threadIdx.x;
    const int wid = j >> 6;
    const int lane = j & 63;

    __shared__ __align__(16) _Float16 pbuf[CK];
    __shared__ __align__(16) float wmax[4];
    __shared__ float mask_lds[CT];
    __shared__ float red[8];

    const float* emB = emissions + (size_t)b * CT * CK;
    const int* tagB = tags + b * CT;
    const int* maskB = mask + b * CT;

    // ---------------- numerator (joint log-likelihood) ----------------
    float num = 0.f;
    for (int t = j; t < CT; t += 256) {
        float mf = maskB[t] ? 1.f : 0.f;
        num += emB[(size_t)t * CK + tagB[t]] * mf;
        if (t >= 1) num += trans[tagB[t - 1] * CK + tagB[t]] * mf;
    }
    #pragma unroll
    for (int off = 32; off > 0; off >>= 1) num += __shfl_down(num, off, 64);
    if (lane == 0) red[wid] = num;
    __syncthreads();
    if (j == 0) ws[CB + b] = red[0] + red[1] + red[2] + red[3];

    // mask as float in LDS (in-loop it is a broadcast ds_read, latency hidden)
    for (int t = j; t < CT; t += 256) mask_lds[t] = maskB[t] ? 1.f : 0.f;

    // ------------- E column j: 32 named uint4 = 128 VGPRs, register-pinned -------------
    MKE(0)  MKE(1)  MKE(2)  MKE(3)  MKE(4)  MKE(5)  MKE(6)  MKE(7)
    MKE(8)  MKE(9)  MKE(10) MKE(11) MKE(12) MKE(13) MKE(14) MKE(15)
    MKE(16) MKE(17) MKE(18) MKE(19) MKE(20) MKE(21) MKE(22) MKE(23)
    MKE(24) MKE(25) MKE(26) MKE(27) MKE(28) MKE(29) MKE(30) MKE(31)
    __syncthreads();

    // ---------------- forward recursion ----------------
    float aj = emB[j];                    // alpha at t=0
    float emit_next = emB[CK + j];        // prefetch t=1

    for (int t = 1; t < CT; ++t) {
        const float emit_t = emit_next;
        const int nxt = (t + 1 < CT) ? (t + 1) : (CT - 1);
        emit_next = emB[(size_t)nxt * CK + j];   // stays in flight across barriers

        // phase A: per-wave max, publish p = exp(a - m_w) <= 1 as f16
        float m = aj;
        #pragma unroll
        for (int off = 1; off < 64; off <<= 1) m = fmaxf(m, __shfl_xor(m, off, 64));
        if (lane == 0) wmax[wid] = m;
        pbuf[j] = (_Float16)__expf(aj - m);
        lds_barrier();

        // phase B: 4 wave-block partial dots (2 acc chains each) + scaled combine
        const float mkf = mask_lds[t];
        float a0 = 0.f, a1 = 0.f;
        DOTC(E0,  0,   a0, a1) DOTC(E1,  8,   a0, a1)
        DOTC(E2,  16,  a0, a1) DOTC(E3,  24,  a0, a1)
        DOTC(E4,  32,  a0, a1) DOTC(E5,  40,  a0, a1)
        DOTC(E6,  48,  a0, a1) DOTC(E7,  56,  a0, a1)
        const float sw0 = a0 + a1;
        float b0 = 0.f, b1 = 0.f;
        DOTC(E8,  64,  b0, b1) DOTC(E9,  72,  b0, b1)
        DOTC(E10, 80,  b0, b1) DOTC(E11, 88,  b0, b1)
        DOTC(E12, 96,  b0, b1) DOTC(E13, 104, b0, b1)
        DOTC(E14, 112, b0, b1) DOTC(E15, 120, b0, b1)
        const float sw1 = b0 + b1;
        float c0 = 0.f, c1 = 0.f;
        DOTC(E16, 128, c0, c1) DOTC(E17, 136, c0, c1)
        DOTC(E18, 144, c0, c1) DOTC(E19, 152, c0, c1)
        DOTC(E20, 160, c0, c1) DOTC(E21, 168, c0, c1)
        DOTC(E22, 176, c0, c1) DOTC(E23, 184, c0, c1)
        const float sw2 = c0 + c1;
        float d0 = 0.f, d1 = 0.f;
        DOTC(E24, 192, d0, d1) DOTC(E25, 200, d0, d1)
        DOTC(E26, 208, d0, d1) DOTC(E27, 216, d0, d1)
        DOTC(E28, 224, d0, d1) DOTC(E29, 232, d0, d1)
        DOTC(E30, 240, d0, d1) DOTC(E31, 248, d0, d1)
        const float sw3 = d0 + d1;

        const float4 wm = *reinterpret_cast<const float4*>(wmax);
        const float M = fmaxf(fmaxf(wm.x, wm.y), fmaxf(wm.z, wm.w));
        float s = __expf(wm.x - M) * sw0;
        s = fmaf(__expf(wm.y - M), sw1, s);
        s = fmaf(__expf(wm.z - M), sw2, s);
        s = fmaf(__expf(wm.w - M), sw3, s);
        const float anew = M + __logf(s) + emit_t;
        aj = (mkf != 0.f) ? anew : aj;
        lds_barrier();   // protect pbuf/wmax reads from next step's writes
    }

    // ---------------- final logsumexp over j ----------------
    float mx = aj;
    #pragma unroll
    for (int off = 32; off > 0; off >>= 1) mx = fmaxf(mx, __shfl_down(mx, off, 64));
    mx = __shfl(mx, 0, 64);
    if (lane == 0) red[wid] = mx;
    __syncthreads();
    const float gmx = fmaxf(fmaxf(red[0], red[1]), fmaxf(red[2], red[3]));
    float ex = __expf(aj - gmx);
    #pragma unroll
    for (int off = 32; off > 0; off >>= 1) ex += __shfl_down(ex, off, 64);
    if (lane == 0) red[4 + wid] = ex;
    __syncthreads();
    if (j == 0) ws[b] = gmx + __logf(red[4] + red[5] + red[6] + red[7]);
}

__global__ void crf_finalize_kernel(const float* __restrict__ ws,
                                    float* __restrict__ out) {
    float v = 0.f;
    if ((int)threadIdx.x < CB) v = ws[threadIdx.x] - ws[CB + threadIdx.x];
    #pragma unroll
    for (int off = 32; off > 0; off >>= 1) v += __shfl_down(v, off, 64);
    if (threadIdx.x == 0) out[0] = v * (1.f / CB);
}

extern "C" void kernel_launch(void* const* d_in, const int* in_sizes, int n_in,
                              void* d_out, int out_size, void* d_ws, size_t ws_size,
                              hipStream_t stream) {
    const float* emissions = (const float*)d_in[0];
    const int* tags = (const int*)d_in[1];
    const int* mask = (const int*)d_in[2];
    const float* trans = (const float*)d_in[3];
    float* out = (float*)d_out;
    float* ws = (float*)d_ws;

    crf_chain_kernel<<<CB, 256, 0, stream>>>(emissions, tags, mask, trans, ws);
    crf_finalize_kernel<<<1, 64, 0, stream>>>(ws, out);
}

// Round 5
// 453.120 us; speedup vs baseline: 2.8398x; 1.1890x over previous
//
#include <hip/hip_runtime.h>
#include <stdint.h>

#define CB 32
#define CT 512
#define CK 256

typedef _Float16 half2_t __attribute__((ext_vector_type(2)));

__device__ inline float dot2f(half2_t a, half2_t b, float c) {
#if __has_builtin(__builtin_amdgcn_fdot2)
    return __builtin_amdgcn_fdot2(a, b, c, false);
#else
    asm("v_dot2_f32_f16 %0, %1, %2, %0" : "+v"(c) : "v"(a), "v"(b));
    return c;
#endif
}

__device__ inline half2_t bch2(float f) { return __builtin_bit_cast(half2_t, f); }
__device__ inline half2_t bch2u(uint32_t u) { return __builtin_bit_cast(half2_t, u); }

__device__ inline uint32_t pk2(float a, float b) {
    return __builtin_bit_cast(uint32_t,
        __builtin_amdgcn_cvt_pkrtz(__expf(a), __expf(b)));
}

// Barrier that drains LDS ops but leaves global-load (vmcnt) prefetches in flight.
__device__ inline void lds_barrier() {
    asm volatile("s_waitcnt lgkmcnt(0)\n\ts_barrier" ::: "memory");
}

// E var n covers transition rows rowbase+8n .. rowbase+8n+7 for column `col`.
#define MKE(n) uint4 E##n; { const float* tp = trans + (size_t)(rowbase + (n) * 8) * CK + col; \
    E##n.x = pk2(tp[0], tp[CK]);                                           \
    E##n.y = pk2(tp[2 * CK], tp[3 * CK]);                                  \
    E##n.z = pk2(tp[4 * CK], tp[5 * CK]);                                  \
    E##n.w = pk2(tp[6 * CK], tp[7 * CK]); }

// 8 p-values (broadcast float4 = 4 half2) dotted against E var EV.
#define DOTC(EV, base, accA, accB) {                                        \
    const float4 q = *reinterpret_cast<const float4*>(&pbuf[(base)]);       \
    accA = dot2f(bch2(q.x), bch2u(EV.x), accA);                             \
    accB = dot2f(bch2(q.y), bch2u(EV.y), accB);                             \
    accA = dot2f(bch2(q.z), bch2u(EV.z), accA);                             \
    accB = dot2f(bch2(q.w), bch2u(EV.w), accB); }

// 512 threads (8 waves) per chain. Thread t: col = t&255, half = t>>8, holds
// E[half*128 .. half*128+127, col] as 16 named uint4 (64 VGPRs) — small enough
// that regalloc keeps it resident (the R3/R4 failure was a 128-VGPR block).
// Per step: [A] threads<256 publish p = exp(a - m_wave) as f16;
//           [B] all threads dot their 128 rows, write 2 wave-block partials;
//           [C] threads<256 combine 4 partials with exp(m_w - M) scales.
__global__ __launch_bounds__(512, 2) void crf_chain_kernel(
    const float* __restrict__ emissions,    // [B,T,K]
    const int* __restrict__ tags,           // [B,T]
    const int* __restrict__ mask,           // [B,T] (bool -> int32)
    const float* __restrict__ trans,        // [K,K]
    float* __restrict__ ws)                 // ws[0..31]=log_den, ws[32..63]=log_num
{
    const int b = blockIdx.x;
    const int tid = threadIdx.x;
    const int col = tid & (CK - 1);
    const int half = tid >> 8;
    const int rowbase = half * 128;
    const int j = tid;                       // alpha owner when tid < CK
    const int wid = tid >> 6;
    const int lane = tid & 63;

    __shared__ __align__(16) _Float16 pbuf[CK];
    __shared__ __align__(16) float wmax[4];
    __shared__ float sbuf[4][CK];
    __shared__ float mask_lds[CT];
    __shared__ float red[8];

    const float* emB = emissions + (size_t)b * CT * CK;
    const int* tagB = tags + b * CT;
    const int* maskB = mask + b * CT;

    // ---------------- numerator (one t per thread: CT == 512) ----------------
    {
        const int t = tid;
        float mf = maskB[t] ? 1.f : 0.f;
        float num = emB[(size_t)t * CK + tagB[t]] * mf;
        if (t >= 1) num += trans[(size_t)tagB[t - 1] * CK + tagB[t]] * mf;
        #pragma unroll
        for (int off = 32; off > 0; off >>= 1) num += __shfl_down(num, off, 64);
        if (lane == 0) red[wid] = num;
        __syncthreads();
        if (tid == 0) {
            float s = 0.f;
            #pragma unroll
            for (int w = 0; w < 8; ++w) s += red[w];
            ws[CB + b] = s;
        }
        mask_lds[tid] = maskB[tid] ? 1.f : 0.f;
    }

    // ------------- E half-column: 16 named uint4 = 64 VGPRs -------------
    MKE(0)  MKE(1)  MKE(2)  MKE(3)  MKE(4)  MKE(5)  MKE(6)  MKE(7)
    MKE(8)  MKE(9)  MKE(10) MKE(11) MKE(12) MKE(13) MKE(14) MKE(15)
    __syncthreads();

    // ---------------- forward recursion ----------------
    float aj = 0.f, emit_next = 0.f;
    if (tid < CK) {
        aj = emB[j];                     // alpha at t=0
        emit_next = emB[CK + j];         // prefetch t=1
    }

    for (int t = 1; t < CT; ++t) {
        float emit_t = emit_next;

        // phase A: alpha owners publish p = exp(a - m_wave) <= 1 as f16
        if (tid < CK) {
            const int nxt = (t + 1 < CT) ? (t + 1) : (CT - 1);
            emit_next = emB[(size_t)nxt * CK + j];   // in flight across barriers
            float m = aj;
            #pragma unroll
            for (int off = 1; off < 64; off <<= 1) m = fmaxf(m, __shfl_xor(m, off, 64));
            if (lane == 0) wmax[wid] = m;
            pbuf[j] = (_Float16)__expf(aj - m);
        }
        lds_barrier();

        // phase B: dot my 128 rows (2 wave-blocks of 64), write partials
        float a0 = 0.f, a1 = 0.f;
        DOTC(E0, rowbase + 0,  a0, a1) DOTC(E1, rowbase + 8,  a0, a1)
        DOTC(E2, rowbase + 16, a0, a1) DOTC(E3, rowbase + 24, a0, a1)
        DOTC(E4, rowbase + 32, a0, a1) DOTC(E5, rowbase + 40, a0, a1)
        DOTC(E6, rowbase + 48, a0, a1) DOTC(E7, rowbase + 56, a0, a1)
        float b0 = 0.f, b1 = 0.f;
        DOTC(E8,  rowbase + 64,  b0, b1) DOTC(E9,  rowbase + 72,  b0, b1)
        DOTC(E10, rowbase + 80,  b0, b1) DOTC(E11, rowbase + 88,  b0, b1)
        DOTC(E12, rowbase + 96,  b0, b1) DOTC(E13, rowbase + 104, b0, b1)
        DOTC(E14, rowbase + 112, b0, b1) DOTC(E15, rowbase + 120, b0, b1)
        sbuf[half * 2 + 0][col] = a0 + a1;
        sbuf[half * 2 + 1][col] = b0 + b1;

        // scales (alpha owners): consume wmax here, before it is overwritten
        float f0 = 0.f, f1 = 0.f, f2 = 0.f, f3 = 0.f, M = 0.f;
        if (tid < CK) {
            const float4 wm = *reinterpret_cast<const float4*>(wmax);
            M = fmaxf(fmaxf(wm.x, wm.y), fmaxf(wm.z, wm.w));
            f0 = __expf(wm.x - M); f1 = __expf(wm.y - M);
            f2 = __expf(wm.z - M); f3 = __expf(wm.w - M);
        }
        lds_barrier();

        // phase C: combine partials, update alpha
        if (tid < CK) {
            float s = f0 * sbuf[0][j];
            s = fmaf(f1, sbuf[1][j], s);
            s = fmaf(f2, sbuf[2][j], s);
            s = fmaf(f3, sbuf[3][j], s);
            const float anew = M + __logf(s) + emit_t;
            aj = (mask_lds[t] != 0.f) ? anew : aj;
        }
        // no third barrier: sbuf reads (here) precede next iteration's bar1;
        // next sbuf writes happen after that bar1.
    }

    // ---------------- final logsumexp over j (alpha owners only) ----------------
    if (tid < CK) {
        float mx = aj;
        #pragma unroll
        for (int off = 32; off > 0; off >>= 1) mx = fmaxf(mx, __shfl_down(mx, off, 64));
        mx = __shfl(mx, 0, 64);
        if (lane == 0) red[wid] = mx;
    }
    __syncthreads();
    if (tid < CK) {
        const float gmx = fmaxf(fmaxf(red[0], red[1]), fmaxf(red[2], red[3]));
        float ex = __expf(aj - gmx);
        #pragma unroll
        for (int off = 32; off > 0; off >>= 1) ex += __shfl_down(ex, off, 64);
        if (lane == 0) red[4 + wid] = ex;
    }
    __syncthreads();
    if (tid == 0) {
        const float gmx = fmaxf(fmaxf(red[0], red[1]), fmaxf(red[2], red[3]));
        ws[b] = gmx + __logf(red[4] + red[5] + red[6] + red[7]);
    }
}

__global__ void crf_finalize_kernel(const float* __restrict__ ws,
                                    float* __restrict__ out) {
    float v = 0.f;
    if ((int)threadIdx.x < CB) v = ws[threadIdx.x] - ws[CB + threadIdx.x];
    #pragma unroll
    for (int off = 32; off > 0; off >>= 1) v += __shfl_down(v, off, 64);
    if (threadIdx.x == 0) out[0] = v * (1.f / CB);
}

extern "C" void kernel_launch(void* const* d_in, const int* in_sizes, int n_in,
                              void* d_out, int out_size, void* d_ws, size_t ws_size,
                              hipStream_t stream) {
    const float* emissions = (const float*)d_in[0];
    const int* tags = (const int*)d_in[1];
    const int* mask = (const int*)d_in[2];
    const float* trans = (const float*)d_in[3];
    float* out = (float*)d_out;
    float* ws = (float*)d_ws;

    crf_chain_kernel<<<CB, 512, 0, stream>>>(emissions, tags, mask, trans, ws);
    crf_finalize_kernel<<<1, 64, 0, stream>>>(ws, out);
}